// Round 4
// baseline (427.626 us; speedup 1.0000x reference)
//
#include <hip/hip_runtime.h>
#include <hip/hip_bf16.h>
#include <stdint.h>

#define B_   64
#define L_   4096
#define H_   128
#define HG_  32            // h-channels per block
#define NG_  4             // h-groups
#define TI_  128           // timesteps per iteration (halved: 2 blocks/CU)
#define NIT_ 32            // iterations (L/TI)
#define PADI 136           // bf16 row stride for inp tile
// swizzle: bijective in h for fixed t; spreads epilogue writes across both
// 16-bank halves (bit4 varies with quad) -> ~2-way (free).
#define SW(t) ((((t) << 2) ^ (t)) & 31)

typedef __attribute__((ext_vector_type(8))) short short8;
typedef __attribute__((ext_vector_type(4))) float floatx4;
typedef __attribute__((ext_vector_type(2))) float floatx2;

#define LOG2E 1.44269504088896340736f

__device__ __forceinline__ unsigned short f2bf(float f){
    unsigned int u = __float_as_uint(f);
    u += 0x7FFFu + ((u >> 16) & 1u);      // RNE
    return (unsigned short)(u >> 16);
}
__device__ __forceinline__ unsigned int pack2(float lo, float hi){
    __hip_bfloat162 h = __float22bfloat162_rn(make_float2(lo, hi));
    return *reinterpret_cast<unsigned int*>(&h);
}

// Fused full-timeline kernel. 256 blocks x 1024 threads, 2 blocks/CU.
// Block (bb, g): batch row bb, h-channels [g*32, g*32+32). Register carry
// h_run across 32 sequential 128-t iterations. LDS = 63.5 KB so two blocks
// co-reside per CU: barrier stalls of one block are hidden by the other.
// 4 barriers/iter: A(inp)|B(mfma+gates)|C1(seg scan)|C2(Kogge); C3 (replay +
// half-wave shfl y-reduce + direct global store) runs barrier-free into next A.
__global__ __launch_bounds__(1024, 8)
void fused_rnn(const float* __restrict__ x,
               const float* __restrict__ Wp, const float* __restrict__ bp,
               const float* __restrict__ Wz, const float* __restrict__ bz,
               const float* __restrict__ Wh, const float* __restrict__ bh,
               const float* __restrict__ Wg,
               float* __restrict__ partials)
{
    __shared__ __align__(16) unsigned short s_inp[TI_*PADI];  // 34816 B (weight staging reuses)
    __shared__ __align__(16) unsigned int  s_ab[TI_*HG_];     // 16384 B (a,th) bf16 pairs
    __shared__ __align__(16) floatx2 s_agg[32*32];            // 8192 B seg aggregates
    __shared__ float s_hh[32*32];                             // 4096 B seg-entry h
    // total 63488 B -> 2 blocks/CU

    const int bid = blockIdx.x;
    const int bb  = bid >> 2;
    const int g   = bid & 3;
    const int tid = threadIdx.x;
    const int wv = tid >> 6, lane = tid & 63, quad = lane >> 4, l15 = lane & 15;

    // --- roles ---
    const int G   = wv >> 3;          // 0: z-gate wave, 1: h-gate wave
    const int tt0 = wv & 7;           // t-tile (8 tiles of 16 t)
    const int sh  = tid & 31;         // C1/C3: h index
    const int ss  = tid >> 5;         // C1/C3: seg index (4 t each)
    const int rh  = tid >> 5;         // C2: h index (segs in-lane)
    const int rs  = tid & 31;         // C2: seg index
    const int cg  = tid & 31;         // inp: k group (4 k)
    const int tg  = tid >> 5;         // inp: t group (4 t)

    // ---- in-kernel weight prep: Wz/Wh -> bf16 [gate][nn][k] in s_inp area ----
    {
        unsigned short* s_w = s_inp;
        const int gate = tid >> 9;            // 0:z 1:h
        const int r    = tid & 511;
        const int k    = r >> 2;              // 0..127
        const int nn0  = (r & 3) * 8;         // 0,8,16,24
        const float* Wsrc = gate ? Wh : Wz;
        const float* p = Wsrc + (size_t)k*H_ + g*HG_ + nn0;
        floatx4 a = *(const floatx4*)p;
        floatx4 b = *(const floatx4*)(p + 4);
        #pragma unroll
        for (int j = 0; j < 4; ++j){
            s_w[gate*4096 + (nn0+j)*H_ + k]   = f2bf(a[j]);
            s_w[gate*4096 + (nn0+4+j)*H_ + k] = f2bf(b[j]);
        }
    }
    __syncthreads();

    // ---- one-time register preloads (frags from staged LDS) ----
    short8 bfr[2][4];
    {
        const unsigned short* wbase = s_inp + G*4096;
        #pragma unroll
        for (int ct = 0; ct < 2; ++ct)
            #pragma unroll
            for (int kk = 0; kk < 4; ++kk)
                bfr[ct][kk] = *(const short8*)&wbase[(ct*16 + l15)*H_ + kk*32 + quad*8];
    }
    float biasv[2];
    #pragma unroll
    for (int ct = 0; ct < 2; ++ct)
        biasv[ct] = (G ? bh : bz)[g*HG_ + ct*16 + l15];
    const float wgv = Wg[g*HG_ + sh];
    float w0[4], w1[4], w2[4], bc[4];
    #pragma unroll
    for (int m = 0; m < 4; ++m){
        w0[m] = Wp[cg*4+m]; w1[m] = Wp[H_+cg*4+m]; w2[m] = Wp[2*H_+cg*4+m];
        bc[m] = bp[cg*4+m];
    }
    float h_run = 0.0f;               // carry (consistent within each h-owner group)
    __syncthreads();                  // frag reads done before s_inp reuse

    float* pbase = partials + (size_t)(g*B_ + bb)*L_;

    for (int it = 0; it < NIT_; ++it){
        // ---- phase A: inp = x @ Wp + bp -> bf16 LDS (direct loads, no prefetch regs) ----
        {
            #pragma unroll
            for (int j = 0; j < 4; ++j){
                int t = tg*4 + j;
                const float* xr = x + ((size_t)bb*L_ + it*TI_ + t)*3;
                float x0 = xr[0], x1 = xr[1], x2 = xr[2];
                float v0 = fmaf(x2, w2[0], fmaf(x1, w1[0], fmaf(x0, w0[0], bc[0])));
                float v1 = fmaf(x2, w2[1], fmaf(x1, w1[1], fmaf(x0, w0[1], bc[1])));
                float v2 = fmaf(x2, w2[2], fmaf(x1, w1[2], fmaf(x0, w0[2], bc[2])));
                float v3 = fmaf(x2, w2[3], fmaf(x1, w1[3], fmaf(x0, w0[3], bc[3])));
                uint2 st; st.x = pack2(v0, v1); st.y = pack2(v2, v3);
                *(uint2*)&s_inp[t*PADI + cg*4] = st;
            }
        }
        __syncthreads();   // BAR1

        // ---- phase B: MFMA (1 tile, both n-halves, gate per wave) + epilogue ----
        {
            floatx4 acc0 = (floatx4){0.f,0.f,0.f,0.f};
            floatx4 acc1 = (floatx4){0.f,0.f,0.f,0.f};
            #pragma unroll
            for (int kk = 0; kk < 4; ++kk){
                short8 af = *(const short8*)&s_inp[(tt0*16 + l15)*PADI + kk*32 + quad*8];
                acc0 = __builtin_amdgcn_mfma_f32_16x16x32_bf16(af, bfr[0][kk], acc0, 0, 0, 0);
                acc1 = __builtin_amdgcn_mfma_f32_16x16x32_bf16(af, bfr[1][kk], acc1, 0, 0, 0);
            }
            #pragma unroll
            for (int ct = 0; ct < 2; ++ct){
                floatx4 acc = ct ? acc1 : acc0;
                int hl = ct*16 + l15;
                #pragma unroll
                for (int e = 0; e < 4; ++e){
                    int t = tt0*16 + quad*4 + e;
                    float v = acc[e] + biasv[ct];
                    float r;
                    if (G == 0){
                        r = __builtin_amdgcn_rcpf(1.0f + __builtin_amdgcn_exp2f(v * LOG2E)); // a = 1-z
                    } else {
                        float ex = __builtin_amdgcn_exp2f(2.0f*LOG2E*v);
                        r = 1.0f - 2.0f*__builtin_amdgcn_rcpf(ex + 1.0f);                    // tanh
                    }
                    ((unsigned short*)s_ab)[(t*HG_ + (hl ^ SW(t)))*2 + G] = f2bf(r);
                }
            }
        }
        __syncthreads();   // BAR2

        // ---- phase C1: per-seg local scan (4 t), a/b kept in regs ----
        float aj[4], bj[4];
        {
            float A = 1.0f, Q = 0.0f;
            #pragma unroll
            for (int j = 0; j < 4; ++j){
                int t = ss*4 + j;
                unsigned int u = s_ab[t*HG_ + (sh ^ SW(t))];
                float a  = __uint_as_float(u << 16);            // lo bf16 (gate a)
                float th = __uint_as_float(u & 0xffff0000u);    // hi bf16 (tanh)
                float b  = fmaf(-a, th, th);                    // (1-a)*th
                aj[j] = a; bj[j] = b;
                Q = fmaf(a, Q, b);
                A *= a;
            }
            s_agg[ss*32 + (sh ^ ss)] = (floatx2){A, Q};
        }
        __syncthreads();   // BAR3

        // ---- phase C2: Kogge-Stone over 32 segs (remapped: segs in-lane) ----
        {
            floatx2 v = s_agg[rs*32 + (rh ^ rs)];
            float P = v[0], Hq = v[1];
            #pragma unroll
            for (int d = 1; d < 32; d <<= 1){
                float pP = __shfl_up(P, d, 32);
                float pH = __shfl_up(Hq, d, 32);
                if (rs >= d){
                    Hq = fmaf(P, pH, Hq);
                    P  = P * pP;
                }
            }
            float eP = __shfl_up(P, 1, 32);
            float eH = __shfl_up(Hq, 1, 32);
            if (rs == 0){ eP = 1.0f; eH = 0.0f; }
            float tP = __shfl(P, 31, 32);
            float tH = __shfl(Hq, 31, 32);
            s_hh[rs*32 + (rh ^ rs)] = fmaf(eP, h_run, eH);   // h at seg entry - 1
            h_run = fmaf(tP, h_run, tH);                     // carry to next iter
        }
        __syncthreads();   // BAR4

        // ---- phase C3: replay 4 steps, half-wave shfl y-reduce, direct store ----
        {
            float hh = s_hh[ss*32 + (sh ^ ss)];
            float y0, y1, y2, y3;
            y0 = wgv * hh; hh = fmaf(aj[0], hh, bj[0]);
            y1 = wgv * hh; hh = fmaf(aj[1], hh, bj[1]);
            y2 = wgv * hh; hh = fmaf(aj[2], hh, bj[2]);
            y3 = wgv * hh; hh = fmaf(aj[3], hh, bj[3]);
            #pragma unroll
            for (int d = 16; d >= 1; d >>= 1){
                y0 += __shfl_xor(y0, d, 32);
                y1 += __shfl_xor(y1, d, 32);
                y2 += __shfl_xor(y2, d, 32);
                y3 += __shfl_xor(y3, d, 32);
            }
            if (sh == 0)
                *(floatx4*)&pbase[it*TI_ + ss*4] = (floatx4){y0, y1, y2, y3};
        }
        // no barrier: C3 reads s_hh (next write is C2, 3 barriers away) + regs only
    }
}

// Gather: preds = bg + sum of 4 group partials (float4-vectorized). 64 blocks.
__global__ __launch_bounds__(1024)
void gather(const floatx4* __restrict__ partials, const float* __restrict__ bg,
            floatx4* __restrict__ preds)
{
    size_t i = (size_t)blockIdx.x*1024 + threadIdx.x;       // 0 .. 65535
    const size_t S = (size_t)B_ * L_ / 4;                   // 65536
    float b = bg[0];
    floatx4 v = partials[i] + partials[S+i] + partials[2*S+i] + partials[3*S+i];
    v[0] += b; v[1] += b; v[2] += b; v[3] += b;
    preds[i] = v;
}

extern "C" void kernel_launch(void* const* d_in, const int* in_sizes, int n_in,
                              void* d_out, int out_size, void* d_ws, size_t ws_size,
                              hipStream_t stream){
    const float* x  = (const float*)d_in[0];
    const float* Wp = (const float*)d_in[1];
    const float* bp = (const float*)d_in[2];
    const float* Wz = (const float*)d_in[3];
    const float* bz = (const float*)d_in[4];
    const float* Wh = (const float*)d_in[5];
    const float* bh = (const float*)d_in[6];
    const float* Wg = (const float*)d_in[7];
    const float* bg = (const float*)d_in[8];
    float* preds = (float*)d_out;

    uint8_t* w8 = (uint8_t*)d_ws;
    float* partials = (float*)w8;                           // 4 MB: [g][bb][l] f32

    hipLaunchKernelGGL(fused_rnn, dim3(B_*NG_), dim3(1024), 0, stream,
                       x, Wp, bp, Wz, bz, Wh, bh, Wg, partials);
    hipLaunchKernelGGL(gather, dim3(B_*L_/4096), dim3(1024), 0, stream,
                       (const floatx4*)partials, bg, (floatx4*)preds);
}

// Round 5
// 162.827 us; speedup vs baseline: 2.6263x; 2.6263x over previous
//
#include <hip/hip_runtime.h>
#include <hip/hip_bf16.h>
#include <stdint.h>

#define B_   64
#define L_   4096
#define H_   128
#define HG_  16            // h-channels per block
#define NG_  8             // h-groups -> 512 blocks, 2 per CU
#define TI_  128           // timesteps per iteration
#define NIT_ 32            // iterations (L/TI)
#define PADI 136           // bf16 row stride for inp tile (272B rows: +4 bank rotate)

// s_ab / s_y row stride 17 u32 + h-swizzle by (t>>2)&15: <=2-way on all accesses
#define ABI(t,h) ((t)*17 + ((h) ^ (((t)>>2) & 15)))

typedef __attribute__((ext_vector_type(8))) short short8;
typedef __attribute__((ext_vector_type(4))) float floatx4;

#define LOG2E 1.44269504088896340736f

__device__ __forceinline__ unsigned short f2bf(float f){
    unsigned int u = __float_as_uint(f);
    u += 0x7FFFu + ((u >> 16) & 1u);      // RNE
    return (unsigned short)(u >> 16);
}
__device__ __forceinline__ unsigned int pack2(float lo, float hi){
    __hip_bfloat162 h = __float22bfloat162_rn(make_float2(lo, hi));
    return *reinterpret_cast<unsigned int*>(&h);
}

// Fused full-timeline kernel. 512 blocks x 512 threads (8 waves), 2 blocks/CU
// (VGPR cap 128 at 4 waves/SIMD -> no spill; two independent barrier domains
// per CU hide each other's barrier stalls). Block (bb,g): batch row bb,
// h-channels [g*16, g*16+16). Register carry h_run across 32 iterations.
// 3 barriers/iter: A(inp) | B(mfma both gates + epilogue) | C(fused scan:
// local scan + 32-wide Kogge + replay, pure registers+shfl) | D(y-reduce+store,
// barrier-free into next A).
__global__ __launch_bounds__(512, 4)
void fused_rnn(const float* __restrict__ x,
               const float* __restrict__ Wp, const float* __restrict__ bp,
               const float* __restrict__ Wz, const float* __restrict__ bz,
               const float* __restrict__ Wh, const float* __restrict__ bh,
               const float* __restrict__ Wg,
               float* __restrict__ partials)
{
    __shared__ __align__(16) unsigned short s_inp[TI_*PADI];  // 34816 B (weight staging overlays)
    __shared__ unsigned int s_ab[TI_*17];                     // 8704 B (a,th) bf16 pairs
    __shared__ float s_y[TI_*17];                             // 8704 B y contributions
    // total 52224 B

    const int bid = blockIdx.x;
    const int bb  = bid >> 3;
    const int g   = bid & 7;
    const int tid = threadIdx.x;
    const int wv = tid >> 6, lane = tid & 63, quad = lane >> 4, l15 = lane & 15;

    // --- roles ---
    const int tg  = tid >> 5;         // A: t group (8 t)
    const int cg  = tid & 31;         // A: k group (4 k)
    const int rh  = tid >> 5;         // C: h channel (0..15)
    const int rs  = tid & 31;         // C: segment (4 t each)
    const int dt  = tid >> 2;         // D: t (0..127)
    const int dp  = tid & 3;          // D: part (4 h each)

    // ---- in-kernel weight prep: Wz/Wh -> bf16 [gate][n][k] in s_inp area ----
    {
        unsigned short* s_w = s_inp;
        const int gate = tid >> 8;            // 0:z 1:h
        const int r    = tid & 255;
        const int n    = r >> 4;              // 0..15
        const int k0   = (r & 15) * 8;
        const float* Wsrc = gate ? Wh : Wz;
        #pragma unroll
        for (int j = 0; j < 8; ++j){
            int k = k0 + j;
            s_w[gate*2048 + n*H_ + k] = f2bf(Wsrc[(size_t)k*H_ + g*HG_ + n]);
        }
    }
    __syncthreads();

    // ---- one-time register preloads ----
    short8 bfr[2][4];                 // both gates' B-frags (32 VGPR)
    #pragma unroll
    for (int G = 0; G < 2; ++G)
        #pragma unroll
        for (int kk = 0; kk < 4; ++kk)
            bfr[G][kk] = *(const short8*)&s_inp[G*2048 + l15*H_ + kk*32 + quad*8];
    const float biasz = bz[g*HG_ + l15];
    const float biash = bh[g*HG_ + l15];
    const float wgv   = Wg[g*HG_ + rh];
    float w0[4], w1[4], w2[4], bc[4];
    #pragma unroll
    for (int m = 0; m < 4; ++m){
        w0[m] = Wp[cg*4+m]; w1[m] = Wp[H_+cg*4+m]; w2[m] = Wp[2*H_+cg*4+m];
        bc[m] = bp[cg*4+m];
    }
    float h_run = 0.0f;               // per-channel carry (consistent in each rh 32-group)
    __syncthreads();                  // frag reads done before s_inp reuse

    float* pbase = partials + (size_t)(g*B_ + bb)*L_;

    for (int it = 0; it < NIT_; ++it){
        // ---- phase A: inp = x @ Wp + bp -> bf16 LDS ----
        {
            #pragma unroll
            for (int j = 0; j < 8; ++j){
                int t = tg*8 + j;
                const float* xr = x + ((size_t)bb*L_ + it*TI_ + t)*3;
                float x0 = xr[0], x1 = xr[1], x2 = xr[2];
                float v0 = fmaf(x2, w2[0], fmaf(x1, w1[0], fmaf(x0, w0[0], bc[0])));
                float v1 = fmaf(x2, w2[1], fmaf(x1, w1[1], fmaf(x0, w0[1], bc[1])));
                float v2 = fmaf(x2, w2[2], fmaf(x1, w1[2], fmaf(x0, w0[2], bc[2])));
                float v3 = fmaf(x2, w2[3], fmaf(x1, w1[3], fmaf(x0, w0[3], bc[3])));
                uint2 st; st.x = pack2(v0, v1); st.y = pack2(v2, v3);
                *(uint2*)&s_inp[t*PADI + cg*4] = st;
            }
        }
        __syncthreads();   // BAR1: s_inp ready

        // ---- phase B: wave wv owns t-tile wv; both gates; write (a,th) u32 ----
        {
            floatx4 accz = (floatx4){0.f,0.f,0.f,0.f};
            floatx4 acch = (floatx4){0.f,0.f,0.f,0.f};
            #pragma unroll
            for (int kk = 0; kk < 4; ++kk){
                short8 af = *(const short8*)&s_inp[(wv*16 + l15)*PADI + kk*32 + quad*8];
                accz = __builtin_amdgcn_mfma_f32_16x16x32_bf16(af, bfr[0][kk], accz, 0, 0, 0);
                acch = __builtin_amdgcn_mfma_f32_16x16x32_bf16(af, bfr[1][kk], acch, 0, 0, 0);
            }
            #pragma unroll
            for (int e = 0; e < 4; ++e){
                int t = wv*16 + quad*4 + e;
                float vz = accz[e] + biasz;
                float a  = __builtin_amdgcn_rcpf(1.0f + __builtin_amdgcn_exp2f(vz * LOG2E)); // a = 1-z
                float vh = acch[e] + biash;
                float ex = __builtin_amdgcn_exp2f(2.0f*LOG2E*vh);
                float th = 1.0f - 2.0f*__builtin_amdgcn_rcpf(ex + 1.0f);                     // tanh
                s_ab[ABI(t, l15)] = pack2(a, th);
            }
        }
        __syncthreads();   // BAR2: s_ab ready

        // ---- phase C: fused scan. thread (rh, rs): 4-step local scan ->
        //      32-wide Kogge over segs -> exclusive entry h -> replay ----
        {
            float aj[4], bj[4];
            float P = 1.0f, Q = 0.0f;
            #pragma unroll
            for (int j = 0; j < 4; ++j){
                int t = rs*4 + j;
                unsigned int u = s_ab[ABI(t, rh)];
                float a  = __uint_as_float(u << 16);            // lo bf16: a
                float th = __uint_as_float(u & 0xffff0000u);    // hi bf16: tanh
                float b  = fmaf(-a, th, th);                    // (1-a)*th
                aj[j] = a; bj[j] = b;
                Q = fmaf(a, Q, b);
                P *= a;
            }
            #pragma unroll
            for (int d = 1; d < 32; d <<= 1){
                float pP = __shfl_up(P, d, 32);
                float pH = __shfl_up(Q, d, 32);
                if (rs >= d){
                    Q = fmaf(P, pH, Q);
                    P = P * pP;
                }
            }
            float eP = __shfl_up(P, 1, 32);
            float eH = __shfl_up(Q, 1, 32);
            if (rs == 0){ eP = 1.0f; eH = 0.0f; }
            float tP = __shfl(P, 31, 32);
            float tH = __shfl(Q, 31, 32);
            float hh = fmaf(eP, h_run, eH);      // h at entry of seg rs (= h_{t0-1})
            h_run = fmaf(tP, h_run, tH);         // carry to next iteration
            #pragma unroll
            for (int j = 0; j < 4; ++j){
                int t = rs*4 + j;
                s_y[ABI(t, rh)] = wgv * hh;      // contribution of channel rh to y_t
                hh = fmaf(aj[j], hh, bj[j]);
            }
        }
        __syncthreads();   // BAR3: s_y ready

        // ---- phase D: y-reduce over 16 h (4 lds + 2 shfl) + store; no barrier ----
        {
            float s = s_y[ABI(dt, dp*4+0)] + s_y[ABI(dt, dp*4+1)]
                    + s_y[ABI(dt, dp*4+2)] + s_y[ABI(dt, dp*4+3)];
            s += __shfl_xor(s, 1, 64);
            s += __shfl_xor(s, 2, 64);
            if (dp == 0)
                pbase[it*TI_ + dt] = s;
        }
        // no barrier: next-iter A writes s_inp (untouched here); next writer of
        // s_y is C(it+1), two barriers away.
    }
}

// Gather: preds = bg + sum of 8 group partials (float4-vectorized). 64 blocks.
__global__ __launch_bounds__(1024)
void gather(const floatx4* __restrict__ partials, const float* __restrict__ bg,
            floatx4* __restrict__ preds)
{
    size_t i = (size_t)blockIdx.x*1024 + threadIdx.x;       // 0 .. 65535
    const size_t S = (size_t)B_ * L_ / 4;                   // 65536
    float b = bg[0];
    floatx4 v = partials[i];
    #pragma unroll
    for (int gg = 1; gg < NG_; ++gg) v += partials[gg*S + i];
    v[0] += b; v[1] += b; v[2] += b; v[3] += b;
    preds[i] = v;
}

extern "C" void kernel_launch(void* const* d_in, const int* in_sizes, int n_in,
                              void* d_out, int out_size, void* d_ws, size_t ws_size,
                              hipStream_t stream){
    const float* x  = (const float*)d_in[0];
    const float* Wp = (const float*)d_in[1];
    const float* bp = (const float*)d_in[2];
    const float* Wz = (const float*)d_in[3];
    const float* bz = (const float*)d_in[4];
    const float* Wh = (const float*)d_in[5];
    const float* bh = (const float*)d_in[6];
    const float* Wg = (const float*)d_in[7];
    const float* bg = (const float*)d_in[8];
    float* preds = (float*)d_out;

    uint8_t* w8 = (uint8_t*)d_ws;
    float* partials = (float*)w8;                           // 8 MB: [g][bb][l] f32

    hipLaunchKernelGGL(fused_rnn, dim3(B_*NG_), dim3(512), 0, stream,
                       x, Wp, bp, Wz, bz, Wh, bh, Wg, partials);
    hipLaunchKernelGGL(gather, dim3(B_*L_/4096), dim3(1024), 0, stream,
                       (const floatx4*)partials, bg, (floatx4*)preds);
}